// Round 2
// 617.942 us; speedup vs baseline: 1.1572x; 1.1572x over previous
//
#include <hip/hip_runtime.h>

// ModulePopHistory: per-item EMA over time prefix, gather at clip(time-1,0), sigmoid.
//   pop_history: [N, 128] float32 (row-major, 512 B/row)
//   time:        [N] int32
//   out:         [N] float32
//
// R2/R3 restructure: the EMA at idx is a closed-form geometric-weighted dot product:
//   ema[idx] = 0.8^idx * x[0] + sum_{t=1..idx} 0.2 * 0.8^(idx-t) * x[t]
// so instead of thread-per-item sequential recurrence (uncoalesced: 64 lanes x 64
// distinct 512B-strided lines per load instr, L1 thrash, latency-bound at 715us vs
// a ~45us memory floor), use 16 lanes per row (4 rows per wave):
//   - lane sub owns elements [8*sub, 8*sub+8): two float4 loads, 32B/lane,
//     contiguous 2KB per wave -> full line utilization
//   - lanes entirely beyond the prefix skip their loads -> fetch ~ prefix bytes
//   - weights: one exp2f per lane (p = 0.8^(idx - t0)) + compile-time constants
//     C_e = 0.2 * 1.25^e  so  weight(t0+e) = C_e * p = 0.2 * 0.8^(idx-t0-e)
//   - 4-step __shfl_xor reduction within each 16-lane group (all 4 rows at once)
//   - the 4 groups' stores are 16B-contiguous -> coalesced writes
// R3 fix: HIP has no __exp2f device intrinsic — use exp2f (emits v_exp_f32).

#define T_STEPS 128

__global__ __launch_bounds__(256) void ModulePopHistory_kernel(
    const float* __restrict__ pop,
    const int* __restrict__ timev,
    float* __restrict__ out,
    int n)
{
    const int lane = threadIdx.x & 63;
    const int g    = lane >> 4;          // group (row slot) within wave: 0..3
    const int sub  = lane & 15;          // lane within group
    const int wave = threadIdx.x >> 6;   // wave within block: 0..3

    const float L08 = -0.32192809488736234f; // log2(0.8)
    // C_e = 0.2 * 1.25^e  (weight(t) = C_e * 0.8^(idx - t0), t = t0 + e)
    const float C1 = 0.25f,        C2 = 0.3125f,       C3 = 0.390625f;
    const float C4 = 0.48828125f,  C5 = 0.6103515625f, C6 = 0.762939453125f;
    const float C7 = 0.95367431640625f;

    const int t0 = sub * 8;              // first element this lane owns

    // 16 rows per block-iteration: 4 waves x 4 rows, contiguous.
    for (int base = blockIdx.x * 16; base < n; base += gridDim.x * 16)
    {
        const int row   = base + wave * 4 + g;
        const bool valid = (row < n);

        int idx = 0;
        if (valid) {
            idx = timev[row] - 1;
            if (idx < 0) idx = 0;        // time in [0,128) -> idx in [0,126]
        }

        const int k0 = idx - t0;         // local prefix length for this lane
        float acc = 0.0f;

        if (valid && k0 >= 0) {
            const float4* rp = (const float4*)(pop + (size_t)row * T_STEPS) + sub * 2;
            const float4 v0 = rp[0];
            const float p = exp2f((float)k0 * L08);   // 0.8^(idx - t0), v_exp_f32

            // e = 0: t == 0 gets weight 0.8^idx (= p for sub==0), else 0.2*p
            const float w0 = (t0 == 0) ? p : 0.2f * p;
            acc = w0 * v0.x;
            acc = fmaf((k0 >= 1) ? C1 * p : 0.0f, v0.y, acc);
            acc = fmaf((k0 >= 2) ? C2 * p : 0.0f, v0.z, acc);
            acc = fmaf((k0 >= 3) ? C3 * p : 0.0f, v0.w, acc);

            if (k0 >= 4) {               // second float4 only if prefix reaches it
                const float4 v1 = rp[1];
                acc = fmaf(C4 * p, v1.x, acc);
                acc = fmaf((k0 >= 5) ? C5 * p : 0.0f, v1.y, acc);
                acc = fmaf((k0 >= 6) ? C6 * p : 0.0f, v1.z, acc);
                acc = fmaf((k0 >= 7) ? C7 * p : 0.0f, v1.w, acc);
            }
        }

        // Reduce within the 16-lane group (serves all 4 rows of the wave at once).
        acc += __shfl_xor(acc, 1, 64);
        acc += __shfl_xor(acc, 2, 64);
        acc += __shfl_xor(acc, 4, 64);
        acc += __shfl_xor(acc, 8, 64);

        if (valid && sub == 0) {
            out[row] = 1.0f / (1.0f + __expf(-acc));
        }
    }
}

extern "C" void kernel_launch(void* const* d_in, const int* in_sizes, int n_in,
                              void* d_out, int out_size, void* d_ws, size_t ws_size,
                              hipStream_t stream) {
    const float* pop = (const float*)d_in[0];
    const int* timev = (const int*)d_in[1];
    // d_in[2] = item_id (unused by the reference output)
    float* out = (float*)d_out;

    int n = in_sizes[1];                 // N_ITEMS (time vector length)
    const int block = 256;
    int grid = (n + 15) / 16;            // 16 rows per block-iteration
    if (grid > 2048) grid = 2048;        // grid-stride the rest
    hipLaunchKernelGGL(ModulePopHistory_kernel, dim3(grid), dim3(block), 0, stream,
                       pop, timev, out, n);
}

// Round 3
// 616.327 us; speedup vs baseline: 1.1603x; 1.0026x over previous
//
#include <hip/hip_runtime.h>

// ModulePopHistory: per-item EMA over time prefix, gather at clip(time-1,0), sigmoid.
//   pop_history: [N, 128] float32 (row-major, 512 B/row)
//   time:        [N] int32
//   out:         [N] float32
//
// Closed form: ema[idx] = 0.8^idx * x[0] + sum_{t=1..idx} 0.2 * 0.8^(idx-t) * x[t]
// 16 lanes per row, 4 rows per wave. R4 changes vs R3:
//  - DENSE load mapping: lane sub loads the row's first half at row*512 + sub*16
//    (elems [4sub,4sub+4)) and the second half at +256 (elems [64+4sub,...)) only
//    when the prefix reaches it. Every 64B memory request is fully consumed by 4
//    lanes (R3's stride-32 16B chunks used 32/64B per request). Rows with idx<64
//    fetch exactly half the row.
//  - timev prefetch: next iteration's time value is loaded before the current
//    iteration's dependent work, hiding its ~L2/HBM latency under compute.
//  - weights: p = 0.8^(idx-4sub) via one exp2f; second half uses q = p * 1.25^64
//    (exact constant), so weight(t0+e) = C_e * {p|q}, C_e = 0.2 * 1.25^e.
// Fetch floor ~290 MB prefix bytes -> ~46 us at 6.3 TB/s; bench dur_us additionally
// carries the harness re-poison fill (~320 us, not ours to optimize).

#define T_STEPS 128

__global__ __launch_bounds__(256) void ModulePopHistory_kernel(
    const float* __restrict__ pop,
    const int* __restrict__ timev,
    float* __restrict__ out,
    int n)
{
    const int lane = threadIdx.x & 63;
    const int g    = lane >> 4;          // group (row slot) within wave: 0..3
    const int sub  = lane & 15;          // lane within group
    const int wave = threadIdx.x >> 6;   // wave within block: 0..3

    const float L08 = -0.32192809488736234f; // log2(0.8)
    // C_e = 0.2 * 1.25^e
    const float C1 = 0.25f, C2 = 0.3125f, C3 = 0.390625f;
    const float INV64 = 1593091.9113f;       // 1.25^64 = 0.8^-64 (exact to fp32)

    const int t0 = sub * 4;              // first element this lane owns (half 0)
    const int stride = gridDim.x * 16;

    int base = blockIdx.x * 16;
    int row  = base + wave * 4 + g;
    int tcur = (row < n) ? timev[row] : 1;

    while (base < n) {
        // Prefetch next iteration's time value before the dependent work.
        const int nbase = base + stride;
        const int nrow  = nbase + wave * 4 + g;
        int tnext = 1;
        if (nbase < n && nrow < n) tnext = timev[nrow];

        int idx = tcur - 1;
        if (idx < 0) idx = 0;            // time in [0,128) -> idx in [0,126]

        const bool valid = (row < n);
        const int k0 = idx - t0;         // local prefix length, half 0
        float acc = 0.0f;

        if (valid && k0 >= 0) {
            const float4* rp = (const float4*)(pop + (size_t)row * T_STEPS);
            const float4 v = rp[sub];                 // dense: bytes [16*sub, 16*sub+16)
            const float p = exp2f((float)k0 * L08);   // 0.8^(idx - t0)

            const float w0 = (sub == 0) ? p : 0.2f * p;  // t==0 gets 0.8^idx
            acc = w0 * v.x;
            acc = fmaf((k0 >= 1) ? C1 * p : 0.0f, v.y, acc);
            acc = fmaf((k0 >= 2) ? C2 * p : 0.0f, v.z, acc);
            acc = fmaf((k0 >= 3) ? C3 * p : 0.0f, v.w, acc);

            const int k1 = k0 - 64;      // local prefix length, half 1 (t = 64+4sub)
            if (k1 >= 0) {
                const float4 u = rp[16 + sub];        // dense: +256B half
                const float q = p * INV64;            // 0.8^k1
                acc = fmaf(0.2f * q, u.x, acc);
                acc = fmaf((k1 >= 1) ? C1 * q : 0.0f, u.y, acc);
                acc = fmaf((k1 >= 2) ? C2 * q : 0.0f, u.z, acc);
                acc = fmaf((k1 >= 3) ? C3 * q : 0.0f, u.w, acc);
            }
        }

        // Reduce within each 16-lane group (all 4 rows of the wave at once).
        acc += __shfl_xor(acc, 1, 64);
        acc += __shfl_xor(acc, 2, 64);
        acc += __shfl_xor(acc, 4, 64);
        acc += __shfl_xor(acc, 8, 64);

        if (valid && sub == 0) {
            out[row] = 1.0f / (1.0f + __expf(-acc));
        }

        base = nbase;
        row  = nrow;
        tcur = tnext;
    }
}

extern "C" void kernel_launch(void* const* d_in, const int* in_sizes, int n_in,
                              void* d_out, int out_size, void* d_ws, size_t ws_size,
                              hipStream_t stream) {
    const float* pop = (const float*)d_in[0];
    const int* timev = (const int*)d_in[1];
    // d_in[2] = item_id (unused by the reference output)
    float* out = (float*)d_out;

    int n = in_sizes[1];                 // N_ITEMS (time vector length)
    const int block = 256;
    int grid = (n + 15) / 16;            // 16 rows per block-iteration
    if (grid > 2048) grid = 2048;        // 8 blocks/CU = full 32 waves/CU occupancy
    hipLaunchKernelGGL(ModulePopHistory_kernel, dim3(grid), dim3(block), 0, stream,
                       pop, timev, out, n);
}